// Round 1
// baseline (6114.986 us; speedup 1.0000x reference)
//
#include <hip/hip_runtime.h>
#include <hip/hip_bf16.h>
#include <math.h>

#define D 384
#define NH 8
#define HD 48
#define KN 10
#define SEQ 14
#define NB 64
#define NN 8192
#define NSEQ (NB * KN)          // 640
#define MROWS (NSEQ * SEQ)      // 8960
#define EPS 1e-5f

// ---------------------------------------------------------------------------
// sim[b][h][n] = sum_d qt[b][h][d] * nd[b][n][d]
// thread-per-n, float4 streaming; qt loads are wave-uniform -> scalar loads.
// ---------------------------------------------------------------------------
__global__ __launch_bounds__(256) void sim_kernel(
    const float* __restrict__ qt, const float* __restrict__ nd,
    float* __restrict__ sim)
{
    const int b = blockIdx.y;
    const int n = blockIdx.x * 256 + threadIdx.x;
    const float* ndr = nd + ((long long)b * NN + n) * D;
    const float* qb  = qt + (long long)b * SEQ * D;
    float p[SEQ];
#pragma unroll
    for (int h = 0; h < SEQ; ++h) p[h] = 0.f;
    for (int k = 0; k < D; k += 4) {
        float4 nv = *(const float4*)(ndr + k);
#pragma unroll
        for (int h = 0; h < SEQ; ++h) {
            float4 qv = *(const float4*)(qb + h * D + k);
            p[h] += nv.x * qv.x + nv.y * qv.y + nv.z * qv.z + nv.w * qv.w;
        }
    }
#pragma unroll
    for (int h = 0; h < SEQ; ++h)
        sim[((long long)b * SEQ + h) * NN + n] = p[h];
}

// ---------------------------------------------------------------------------
// top-10 per row of 8192, jax tie-break (equal value -> lower index first)
// ---------------------------------------------------------------------------
__global__ __launch_bounds__(256) void topk_kernel(
    const float* __restrict__ sim, int* __restrict__ idxOut)
{
    __shared__ float row[NN];
    __shared__ float bv[256];
    __shared__ int   bi[256];
    const int bh = blockIdx.x;   // b*14 + h
    const float* sr = sim + (long long)bh * NN;
    for (int j = threadIdx.x; j < NN; j += 256) row[j] = sr[j];
    __syncthreads();
    for (int r = 0; r < KN; ++r) {
        float best = -INFINITY; int bidx = 0x7fffffff;
        for (int j = threadIdx.x; j < NN; j += 256) {
            float v = row[j];
            if (v > best || (v == best && j < bidx)) { best = v; bidx = j; }
        }
        bv[threadIdx.x] = best; bi[threadIdx.x] = bidx;
        __syncthreads();
        for (int s = 128; s > 0; s >>= 1) {
            if (threadIdx.x < s) {
                float ov = bv[threadIdx.x + s]; int oi = bi[threadIdx.x + s];
                if (ov > bv[threadIdx.x] ||
                    (ov == bv[threadIdx.x] && oi < bi[threadIdx.x])) {
                    bv[threadIdx.x] = ov; bi[threadIdx.x] = oi;
                }
            }
            __syncthreads();
        }
        if (threadIdx.x == 0) {
            idxOut[bh * KN + r] = bi[0];
            row[bi[0]] = -INFINITY;
        }
        __syncthreads();
    }
}

// ---------------------------------------------------------------------------
// build x (= broadcast qt) and mem (= gathered nd rows)
// seq = b*KN + k2 ; x[seq][s][:] = qt[b][s][:], mem[seq][s][:] = nd[b, idx[b,s,k2]]
// ---------------------------------------------------------------------------
__global__ __launch_bounds__(256) void build_kernel(
    const float* __restrict__ qt, const float* __restrict__ nd,
    const int* __restrict__ idx, float* __restrict__ x, float* __restrict__ mem)
{
    const int seq = blockIdx.x;
    const int b = seq / KN, k2 = seq - b * KN;
    for (int i = threadIdx.x; i < SEQ * D; i += 256) {
        const int s = i / D, d = i - s * D;
        x[(long long)seq * SEQ * D + i] = qt[(long long)b * SEQ * D + i];
        const int nsel = idx[(b * SEQ + s) * KN + k2];
        mem[(long long)seq * SEQ * D + i] =
            nd[((long long)b * NN + nsel) * D + d];
    }
}

// ---------------------------------------------------------------------------
// LayerNorm over D=384, one block (128 threads) per row
// ---------------------------------------------------------------------------
__global__ __launch_bounds__(128) void ln_kernel(
    const float* __restrict__ in, const float* __restrict__ w,
    const float* __restrict__ b, float* __restrict__ out)
{
    __shared__ float red[2];
    const long long row = blockIdx.x;
    const float* xr = in + row * D;
    const int t = threadIdx.x;
    float v0 = xr[t], v1 = xr[t + 128], v2 = xr[t + 256];
    float s = v0 + v1 + v2;
#pragma unroll
    for (int o = 32; o > 0; o >>= 1) s += __shfl_xor(s, o, 64);
    if ((t & 63) == 0) red[t >> 6] = s;
    __syncthreads();
    const float mu = (red[0] + red[1]) * (1.f / (float)D);
    __syncthreads();
    const float d0 = v0 - mu, d1 = v1 - mu, d2 = v2 - mu;
    s = d0 * d0 + d1 * d1 + d2 * d2;
#pragma unroll
    for (int o = 32; o > 0; o >>= 1) s += __shfl_xor(s, o, 64);
    if ((t & 63) == 0) red[t >> 6] = s;
    __syncthreads();
    const float r = rsqrtf((red[0] + red[1]) * (1.f / (float)D) + EPS);
    out[row * D + t]       = d0 * r * w[t]       + b[t];
    out[row * D + 128 + t] = d1 * r * w[t + 128] + b[t + 128];
    out[row * D + 256 + t] = d2 * r * w[t + 256] + b[t + 256];
}

// ---------------------------------------------------------------------------
// C[M][N] = A[M][K] @ W[N][K]^T + bias[N]  (+res[M][N])  (optional exact GELU)
// 64x64 tile, 4x4 per thread, k-major LDS (pad 68), float4 LDS reads.
// All of M,N divisible by 64; K divisible by 16.
// ---------------------------------------------------------------------------
__global__ __launch_bounds__(256) void gemm_kernel(
    const float* __restrict__ A, const float* __restrict__ W,
    const float* __restrict__ bias, const float* __restrict__ res,
    float* __restrict__ C, int M, int N, int K, int act)
{
    __shared__ float As[16][68];
    __shared__ float Ws[16][68];
    const int tid = threadIdx.x;
    const int tx = tid & 15, ty = tid >> 4;
    const int row0 = blockIdx.y * 64, col0 = blockIdx.x * 64;
    const int lr = tid >> 2;            // 0..63
    const int lk = (tid & 3) << 2;      // 0,4,8,12
    float acc[4][4] = {{0.f}};
    const float* Aptr = A + (long long)(row0 + lr) * K + lk;
    const float* Wptr = W + (long long)(col0 + lr) * K + lk;
    for (int k0 = 0; k0 < K; k0 += 16) {
        float4 av = *(const float4*)(Aptr + k0);
        float4 wv = *(const float4*)(Wptr + k0);
        As[lk + 0][lr] = av.x; As[lk + 1][lr] = av.y;
        As[lk + 2][lr] = av.z; As[lk + 3][lr] = av.w;
        Ws[lk + 0][lr] = wv.x; Ws[lk + 1][lr] = wv.y;
        Ws[lk + 2][lr] = wv.z; Ws[lk + 3][lr] = wv.w;
        __syncthreads();
#pragma unroll
        for (int kk = 0; kk < 16; ++kk) {
            float4 a = *(const float4*)&As[kk][ty * 4];
            float4 w = *(const float4*)&Ws[kk][tx * 4];
            acc[0][0] += a.x * w.x; acc[0][1] += a.x * w.y;
            acc[0][2] += a.x * w.z; acc[0][3] += a.x * w.w;
            acc[1][0] += a.y * w.x; acc[1][1] += a.y * w.y;
            acc[1][2] += a.y * w.z; acc[1][3] += a.y * w.w;
            acc[2][0] += a.z * w.x; acc[2][1] += a.z * w.y;
            acc[2][2] += a.z * w.z; acc[2][3] += a.z * w.w;
            acc[3][0] += a.w * w.x; acc[3][1] += a.w * w.y;
            acc[3][2] += a.w * w.z; acc[3][3] += a.w * w.w;
        }
        __syncthreads();
    }
#pragma unroll
    for (int i = 0; i < 4; ++i) {
        const long long r = row0 + ty * 4 + i;
#pragma unroll
        for (int j = 0; j < 4; ++j) {
            const int c = col0 + tx * 4 + j;
            float v = acc[i][j] + bias[c];
            if (res) v += res[r * N + c];
            if (act) v = 0.5f * v * (1.f + erff(v * 0.70710678118654752f));
            C[r * N + c] = v;
        }
    }
}

// ---------------------------------------------------------------------------
// attention: one block per (seq, head); S=T=14, HD=48
// Q row layout: Q[(seq*14+s)*qstride + h*48 + e]
// K/V from KV with kstride, koff/voff column offsets.
// O written as (seq,s,D) with D index h*48+e.
// ---------------------------------------------------------------------------
__global__ __launch_bounds__(256) void attn_kernel(
    const float* __restrict__ Q, int qstride,
    const float* __restrict__ KV, int kstride, int koff, int voff,
    float* __restrict__ O)
{
    __shared__ float qs[SEQ][HD], ks[SEQ][HD], vs[SEQ][HD];
    __shared__ float sc[SEQ][SEQ + 1];
    const int seq = blockIdx.x, h = blockIdx.y;
    const int t = threadIdx.x;
    const long long base = (long long)seq * SEQ;
    for (int i = t; i < SEQ * HD; i += 256) {
        const int s = i / HD, e = i - s * HD;
        qs[s][e] = Q[(base + s) * qstride + h * HD + e];
        ks[s][e] = KV[(base + s) * kstride + koff + h * HD + e];
        vs[s][e] = KV[(base + s) * kstride + voff + h * HD + e];
    }
    __syncthreads();
    if (t < SEQ * SEQ) {
        const int i = t / SEQ, j = t - i * SEQ;
        float s = 0.f;
#pragma unroll
        for (int e = 0; e < HD; ++e) s += qs[i][e] * ks[j][e];
        sc[i][j] = s * 0.14433756729740643f;   // 1/sqrt(48)
    }
    __syncthreads();
    if (t < SEQ) {
        float m = -INFINITY;
        for (int j = 0; j < SEQ; ++j) m = fmaxf(m, sc[t][j]);
        float sum = 0.f;
        for (int j = 0; j < SEQ; ++j) {
            const float e = expf(sc[t][j] - m);
            sc[t][j] = e; sum += e;
        }
        const float rr = 1.f / sum;
        for (int j = 0; j < SEQ; ++j) sc[t][j] *= rr;
    }
    __syncthreads();
    for (int i = t; i < SEQ * HD; i += 256) {
        const int s = i / HD, e = i - s * HD;
        float o = 0.f;
#pragma unroll
        for (int j = 0; j < SEQ; ++j) o += sc[s][j] * vs[j][e];
        O[(base + s) * D + h * HD + e] = o;
    }
}

__global__ __launch_bounds__(256) void copy_kernel(
    float4* __restrict__ dst, const float4* __restrict__ src)
{
    const long long i = (long long)blockIdx.x * 256 + threadIdx.x;
    dst[i] = src[i];
}

// ---------------------------------------------------------------------------
extern "C" void kernel_launch(void* const* d_in, const int* in_sizes, int n_in,
                              void* d_out, int out_size, void* d_ws, size_t ws_size,
                              hipStream_t stream)
{
    const float* qt_emb = (const float*)d_in[0];
    const float* nd_emb = (const float*)d_in[1];
    const float* sa_w  = (const float*)d_in[2];
    const float* sa_b  = (const float*)d_in[3];
    const float* sa_ow = (const float*)d_in[4];
    const float* sa_ob = (const float*)d_in[5];
    const float* ca_w  = (const float*)d_in[6];
    const float* ca_b  = (const float*)d_in[7];
    const float* ca_ow = (const float*)d_in[8];
    const float* ca_ob = (const float*)d_in[9];
    const float* ln1w  = (const float*)d_in[10];
    const float* ln1b  = (const float*)d_in[11];
    const float* ln2w  = (const float*)d_in[12];
    const float* ln2b  = (const float*)d_in[13];
    const float* ln3w  = (const float*)d_in[14];
    const float* ln3b  = (const float*)d_in[15];
    const float* f1w   = (const float*)d_in[16];
    const float* f1b   = (const float*)d_in[17];
    const float* f2w   = (const float*)d_in[18];
    const float* f2b   = (const float*)d_in[19];
    const float* fnw   = (const float*)d_in[20];
    const float* fnb   = (const float*)d_in[21];

    float* ws = (float*)d_ws;
    // workspace layout (floats)
    int*   idxb = (int*)ws;                       // 8960 ints
    float* x    = ws + 8960;                      // 8960*384
    float* memb = x    + (long long)MROWS * D;    // 8960*384
    float* mem2 = memb + (long long)MROWS * D;
    float* hbuf = mem2 + (long long)MROWS * D;
    float* qkv  = hbuf + (long long)MROWS * D;    // 8960*1152
    float* qbuf = qkv  + (long long)MROWS * 1152;
    float* kvbuf= qbuf + (long long)MROWS * D;    // 8960*768
    float* obuf = kvbuf+ (long long)MROWS * 768;
    float* ffn1 = obuf + (long long)MROWS * D;    // 8960*1536
    float* simb = qkv;  // sim (64*14*8192 = 7.34M floats) overlaps qkv region

    // phase 1: retrieval
    sim_kernel<<<dim3(NN / 256, NB), 256, 0, stream>>>(qt_emb, nd_emb, simb);
    topk_kernel<<<NB * SEQ, 256, 0, stream>>>(simb, idxb);
    build_kernel<<<NSEQ, 256, 0, stream>>>(qt_emb, nd_emb, idxb, x, memb);

    auto gemm = [&](const float* A, const float* W, const float* bias,
                    const float* res, float* C, int N, int K, int act) {
        gemm_kernel<<<dim3(N / 64, MROWS / 64), 256, 0, stream>>>(
            A, W, bias, res, C, MROWS, N, K, act);
    };

    // phase 2: transformer
    for (int i = 0; i < 6; ++i) {
        const float* memory = (i < 3) ? memb : mem2;
        // self-attention
        ln_kernel<<<MROWS, 128, 0, stream>>>(x, ln1w + i * D, ln1b + i * D, hbuf);
        gemm(hbuf, sa_w + (long long)i * 1152 * D, sa_b + i * 1152, nullptr,
             qkv, 1152, D, 0);
        attn_kernel<<<dim3(NSEQ, NH), 256, 0, stream>>>(
            qkv, 1152, qkv, 1152, 384, 768, obuf);
        gemm(obuf, sa_ow + (long long)i * D * D, sa_ob + i * D, x, x, D, D, 0);
        // cross-attention
        ln_kernel<<<MROWS, 128, 0, stream>>>(x, ln2w + i * D, ln2b + i * D, hbuf);
        gemm(hbuf, ca_w + (long long)i * 1152 * D, ca_b + i * 1152, nullptr,
             qbuf, D, D, 0);
        gemm(memory, ca_w + (long long)i * 1152 * D + 384 * D,
             ca_b + i * 1152 + 384, nullptr, kvbuf, 768, D, 0);
        attn_kernel<<<dim3(NSEQ, NH), 256, 0, stream>>>(
            qbuf, 384, kvbuf, 768, 0, 384, obuf);
        gemm(obuf, ca_ow + (long long)i * D * D, ca_ob + i * D, x, x, D, D, 0);
        // ffn
        ln_kernel<<<MROWS, 128, 0, stream>>>(x, ln3w + i * D, ln3b + i * D, hbuf);
        gemm(hbuf, f1w + (long long)i * 1536 * D, f1b + i * 1536, nullptr,
             ffn1, 1536, D, 1);
        gemm(ffn1, f2w + (long long)i * D * 1536, f2b + i * D, x, x, D, 1536, 0);
        if (i == 2) {
            ln_kernel<<<MROWS, 128, 0, stream>>>(x, fnw, fnb, mem2);
            copy_kernel<<<(MROWS * D) / 1024, 256, 0, stream>>>(
                (float4*)x, (const float4*)mem2);
        }
    }
    ln_kernel<<<MROWS, 128, 0, stream>>>(x, fnw + D, fnb + D, (float*)d_out);
}

// Round 2
// 3501.301 us; speedup vs baseline: 1.7465x; 1.7465x over previous
//
#include <hip/hip_runtime.h>
#include <math.h>

#define D 384
#define NH 8
#define HD 48
#define KN 10
#define SEQ 14
#define NB 64
#define NN 8192
#define NSEQ (NB * KN)          // 640
#define MROWS (NSEQ * SEQ)      // 8960
#define EPS 1e-5f

typedef __attribute__((ext_vector_type(8))) short short8;
typedef __attribute__((ext_vector_type(4))) float floatx4;

__device__ __forceinline__ unsigned short f2bf(float f) {
    unsigned int u = __builtin_bit_cast(unsigned int, f);
    u += 0x7fffu + ((u >> 16) & 1u);
    return (unsigned short)(u >> 16);
}
__device__ __forceinline__ float bf2f(unsigned short h) {
    return __builtin_bit_cast(float, (unsigned int)h << 16);
}
__device__ __forceinline__ void gl_lds16(const void* g, void* l) {
    __builtin_amdgcn_global_load_lds(
        (const __attribute__((address_space(1))) void*)g,
        (__attribute__((address_space(3))) void*)l, 16, 0, 0);
}

// ---------------------------------------------------------------------------
// sim[b][h][n] = sum_d qt[b][h][d] * nd[b][n][d]
// 128 nd-rows staged in LDS (coalesced, every line fully used); qt via
// wave-uniform scalar loads. Threads: r = t&127 (row), half = t>>7 (k-half).
// ---------------------------------------------------------------------------
__global__ __launch_bounds__(256) void sim_kernel(
    const float* __restrict__ qt, const float* __restrict__ nd,
    float* __restrict__ sim)
{
    __shared__ float4 tile[128][25];     // pitch 25 float4 (100 dwords)
    __shared__ float part[128][SEQ];
    const int b = blockIdx.y;
    const int n0 = blockIdx.x * 128;
    const int t = threadIdx.x;
    const int r = t & 127;
    const int cbase = __builtin_amdgcn_readfirstlane((t >> 7) * 12); // float4 col base
    const float* ndb = nd + ((long long)b * NN + n0) * D;
    const float* qb  = qt + (long long)b * SEQ * D;
    float p[SEQ];
#pragma unroll
    for (int h = 0; h < SEQ; ++h) p[h] = 0.f;

    for (int kc = 0; kc < 4; ++kc) {
        // stage 128 rows x 24 float4 (coalesced: 24 consecutive float4 per row)
#pragma unroll
        for (int it = 0; it < 12; ++it) {
            const int idx = it * 256 + t;          // 0..3071
            const int rr = idx / 24, cc = idx - rr * 24;
            tile[rr][cc] = *(const float4*)(ndb + rr * D + kc * 96 + cc * 4);
        }
        __syncthreads();
#pragma unroll
        for (int i = 0; i < 12; ++i) {
            const float4 nv = tile[r][cbase + i];
            const float* qkp = qb + kc * 96 + (cbase + i) * 4;
#pragma unroll
            for (int h = 0; h < SEQ; ++h) {
                const float4 qv = *(const float4*)(qkp + h * D);  // uniform -> s_load
                p[h] += nv.x * qv.x + nv.y * qv.y + nv.z * qv.z + nv.w * qv.w;
            }
        }
        __syncthreads();
    }
    if (t >= 128) {
#pragma unroll
        for (int h = 0; h < SEQ; ++h) part[r][h] = p[h];
    }
    __syncthreads();
    if (t < 128) {
#pragma unroll
        for (int h = 0; h < SEQ; ++h)
            sim[((long long)b * SEQ + h) * NN + n0 + r] = p[h] + part[r][h];
    }
}

// ---------------------------------------------------------------------------
// top-10 per row of 8192, jax tie-break (equal value -> lower index first)
// ---------------------------------------------------------------------------
__global__ __launch_bounds__(256) void topk_kernel(
    const float* __restrict__ sim, int* __restrict__ idxOut)
{
    __shared__ float row[NN];
    __shared__ float bv[256];
    __shared__ int   bi[256];
    const int bh = blockIdx.x;   // b*14 + h
    const float* sr = sim + (long long)bh * NN;
    for (int j = threadIdx.x; j < NN; j += 256) row[j] = sr[j];
    __syncthreads();
    for (int r = 0; r < KN; ++r) {
        float best = -INFINITY; int bidx = 0x7fffffff;
        for (int j = threadIdx.x; j < NN; j += 256) {
            float v = row[j];
            if (v > best || (v == best && j < bidx)) { best = v; bidx = j; }
        }
        bv[threadIdx.x] = best; bi[threadIdx.x] = bidx;
        __syncthreads();
        for (int s = 128; s > 0; s >>= 1) {
            if (threadIdx.x < s) {
                float ov = bv[threadIdx.x + s]; int oi = bi[threadIdx.x + s];
                if (ov > bv[threadIdx.x] ||
                    (ov == bv[threadIdx.x] && oi < bi[threadIdx.x])) {
                    bv[threadIdx.x] = ov; bi[threadIdx.x] = oi;
                }
            }
            __syncthreads();
        }
        if (threadIdx.x == 0) {
            idxOut[bh * KN + r] = bi[0];
            row[bi[0]] = -INFINITY;
        }
        __syncthreads();
    }
}

// ---------------------------------------------------------------------------
// build x (fp32 broadcast qt) and mem (bf16 gathered nd rows)
// ---------------------------------------------------------------------------
__global__ __launch_bounds__(256) void build_kernel(
    const float* __restrict__ qt, const float* __restrict__ nd,
    const int* __restrict__ idx, float* __restrict__ x,
    unsigned short* __restrict__ mem)
{
    const int seq = blockIdx.x;
    const int b = seq / KN, k2 = seq - b * KN;
    for (int i = threadIdx.x; i < SEQ * D; i += 256) {
        const int s = i / D, d = i - s * D;
        x[(long long)seq * SEQ * D + i] = qt[(long long)b * SEQ * D + i];
        const int nsel = idx[(b * SEQ + s) * KN + k2];
        mem[(long long)seq * SEQ * D + i] =
            f2bf(nd[((long long)b * NN + nsel) * D + d]);
    }
}

// ---------------------------------------------------------------------------
// LayerNorm over D=384, one block (128 threads) per row; fp32 in.
// OB=1: out is bf16; OB=0: out is fp32. out2 (optional): bf16 copy.
// ---------------------------------------------------------------------------
template<int OB>
__global__ __launch_bounds__(128) void ln_kernel(
    const float* __restrict__ in, const float* __restrict__ w,
    const float* __restrict__ b, void* __restrict__ out,
    unsigned short* __restrict__ out2)
{
    __shared__ float red[2];
    const long long row = blockIdx.x;
    const float* xr = in + row * D;
    const int t = threadIdx.x;
    float v0 = xr[t], v1 = xr[t + 128], v2 = xr[t + 256];
    float s = v0 + v1 + v2;
#pragma unroll
    for (int o = 32; o > 0; o >>= 1) s += __shfl_xor(s, o, 64);
    if ((t & 63) == 0) red[t >> 6] = s;
    __syncthreads();
    const float mu = (red[0] + red[1]) * (1.f / (float)D);
    __syncthreads();
    const float d0 = v0 - mu, d1 = v1 - mu, d2 = v2 - mu;
    s = d0 * d0 + d1 * d1 + d2 * d2;
#pragma unroll
    for (int o = 32; o > 0; o >>= 1) s += __shfl_xor(s, o, 64);
    if ((t & 63) == 0) red[t >> 6] = s;
    __syncthreads();
    const float r = rsqrtf((red[0] + red[1]) * (1.f / (float)D) + EPS);
    const float o0 = d0 * r * w[t]       + b[t];
    const float o1 = d1 * r * w[t + 128] + b[t + 128];
    const float o2 = d2 * r * w[t + 256] + b[t + 256];
    if (OB) {
        unsigned short* op = (unsigned short*)out;
        op[row * D + t] = f2bf(o0); op[row * D + 128 + t] = f2bf(o1);
        op[row * D + 256 + t] = f2bf(o2);
    } else {
        float* op = (float*)out;
        op[row * D + t] = o0; op[row * D + 128 + t] = o1;
        op[row * D + 256 + t] = o2;
    }
    if (out2) {
        out2[row * D + t] = f2bf(o0); out2[row * D + 128 + t] = f2bf(o1);
        out2[row * D + 256 + t] = f2bf(o2);
    }
}

// ---------------------------------------------------------------------------
// bf16 MFMA GEMM: C[M][N] = A[M][K] @ W[N][K]^T + bias (+res) (opt GELU)
// BM=128, BK=64; BN in {64,128}. global_load_lds width-16 staging with
// XOR-swizzled source chunk order (bank-conflict reduction on frag reads).
// Wave grid 2x2; wave tile 64 x (BN/2); 16x16x32 MFMA.
// ---------------------------------------------------------------------------
template<int BN, int OB, int ACT, int RES>
__global__ __launch_bounds__(256) void mm_kernel(
    const unsigned short* __restrict__ A, const unsigned short* __restrict__ W,
    const float* __restrict__ bias, const float* __restrict__ res,
    void* __restrict__ Cout, int M, int N, int K)
{
    constexpr int NJ = BN / 32;                // n-tiles per wave
    __shared__ __attribute__((aligned(16))) unsigned short As[128 * 64];
    __shared__ __attribute__((aligned(16))) unsigned short Bs[BN * 64];
    const int tid  = threadIdx.x;
    const int wave = __builtin_amdgcn_readfirstlane(tid >> 6);
    const int lane = tid & 63;
    const int wm = wave >> 1, wn = wave & 1;
    const int fm = lane & 15;                  // m/n within 16-tile
    const int fq = lane >> 4;                  // quad
    const int row0 = blockIdx.y * 128;
    const int col0 = blockIdx.x * BN;

    floatx4 acc[4][NJ];
#pragma unroll
    for (int i = 0; i < 4; ++i)
#pragma unroll
        for (int j = 0; j < NJ; ++j) acc[i][j] = (floatx4){0.f, 0.f, 0.f, 0.f};

    for (int k0 = 0; k0 < K; k0 += 64) {
        const unsigned short* Abase = A + (size_t)row0 * K + k0;
#pragma unroll
        for (int j = 0; j < 4; ++j) {          // 1024 A-chunks
            const int L = j * 256 + tid;
            const int r = L >> 3, cp = L & 7;
            const int cl = cp ^ (r & 7);
            gl_lds16(Abase + r * K + cl * 8, As + (j * 256 + wave * 64) * 8);
        }
        const unsigned short* Bbase = W + (size_t)col0 * K + k0;
#pragma unroll
        for (int j = 0; j < BN / 32; ++j) {    // BN*8 B-chunks
            const int L = j * 256 + tid;
            const int r = L >> 3, cp = L & 7;
            const int cl = cp ^ (r & 7);
            gl_lds16(Bbase + r * K + cl * 8, Bs + (j * 256 + wave * 64) * 8);
        }
        __syncthreads();
#pragma unroll
        for (int s = 0; s < 2; ++s) {
            short8 af[4], bfr[NJ];
#pragma unroll
            for (int i = 0; i < 4; ++i) {
                const int ra = wm * 64 + i * 16 + fm;
                const int cp = (s * 4 + fq) ^ (ra & 7);
                af[i] = *(const short8*)(As + (ra * 8 + cp) * 8);
            }
#pragma unroll
            for (int j = 0; j < NJ; ++j) {
                const int rb = wn * (BN / 2) + j * 16 + fm;
                const int cp = (s * 4 + fq) ^ (rb & 7);
                bfr[j] = *(const short8*)(Bs + (rb * 8 + cp) * 8);
            }
#pragma unroll
            for (int i = 0; i < 4; ++i)
#pragma unroll
                for (int j = 0; j < NJ; ++j)
                    acc[i][j] = __builtin_amdgcn_mfma_f32_16x16x32_bf16(
                        af[i], bfr[j], acc[i][j], 0, 0, 0);
        }
        __syncthreads();
    }
    // epilogue: D layout col=lane&15, row=quad*4+reg
#pragma unroll
    for (int i = 0; i < 4; ++i) {
#pragma unroll
        for (int rg = 0; rg < 4; ++rg) {
            const int rr = row0 + wm * 64 + i * 16 + fq * 4 + rg;
            const size_t rb = (size_t)rr * N;
#pragma unroll
            for (int j = 0; j < NJ; ++j) {
                const int cc = col0 + wn * (BN / 2) + j * 16 + fm;
                float v = acc[i][j][rg] + bias[cc];
                if (RES) v += res[rb + cc];
                if (ACT) v = 0.5f * v * (1.f + erff(v * 0.70710678118654752f));
                if (OB) ((unsigned short*)Cout)[rb + cc] = f2bf(v);
                else    ((float*)Cout)[rb + cc] = v;
            }
        }
    }
}

// ---------------------------------------------------------------------------
// attention: one block per (seq, head); S=T=14, HD=48; bf16 in/out, fp32 math
// ---------------------------------------------------------------------------
__global__ __launch_bounds__(256) void attn_kernel(
    const unsigned short* __restrict__ Q, int qstride,
    const unsigned short* __restrict__ KV, int kstride, int koff, int voff,
    unsigned short* __restrict__ O)
{
    __shared__ float qs[SEQ][HD], ks[SEQ][HD], vs[SEQ][HD];
    __shared__ float sc[SEQ][SEQ + 1];
    const int seq = blockIdx.x, h = blockIdx.y;
    const int t = threadIdx.x;
    const long long base = (long long)seq * SEQ;
    for (int i = t; i < SEQ * HD; i += 256) {
        const int s = i / HD, e = i - s * HD;
        qs[s][e] = bf2f(Q[(base + s) * qstride + h * HD + e]);
        ks[s][e] = bf2f(KV[(base + s) * kstride + koff + h * HD + e]);
        vs[s][e] = bf2f(KV[(base + s) * kstride + voff + h * HD + e]);
    }
    __syncthreads();
    if (t < SEQ * SEQ) {
        const int i = t / SEQ, j = t - i * SEQ;
        float s = 0.f;
#pragma unroll
        for (int e = 0; e < HD; ++e) s += qs[i][e] * ks[j][e];
        sc[i][j] = s * 0.14433756729740643f;   // 1/sqrt(48)
    }
    __syncthreads();
    if (t < SEQ) {
        float m = -INFINITY;
        for (int j = 0; j < SEQ; ++j) m = fmaxf(m, sc[t][j]);
        float sum = 0.f;
        for (int j = 0; j < SEQ; ++j) {
            const float e = expf(sc[t][j] - m);
            sc[t][j] = e; sum += e;
        }
        const float rr = 1.f / sum;
        for (int j = 0; j < SEQ; ++j) sc[t][j] *= rr;
    }
    __syncthreads();
    for (int i = t; i < SEQ * HD; i += 256) {
        const int s = i / HD, e = i - s * HD;
        float o = 0.f;
#pragma unroll
        for (int j = 0; j < SEQ; ++j) o += sc[s][j] * vs[j][e];
        O[(base + s) * D + h * HD + e] = f2bf(o);
    }
}

// ---------------------------------------------------------------------------
// fp32 -> bf16 weight conversion (n4 = element count / 4)
// ---------------------------------------------------------------------------
__global__ __launch_bounds__(256) void cvt_kernel(
    const float4* __restrict__ in, ushort4* __restrict__ out, int n4)
{
    const int i = blockIdx.x * 256 + threadIdx.x;
    if (i < n4) {
        const float4 v = in[i];
        ushort4 o;
        o.x = f2bf(v.x); o.y = f2bf(v.y); o.z = f2bf(v.z); o.w = f2bf(v.w);
        out[i] = o;
    }
}

// ---------------------------------------------------------------------------
extern "C" void kernel_launch(void* const* d_in, const int* in_sizes, int n_in,
                              void* d_out, int out_size, void* d_ws, size_t ws_size,
                              hipStream_t stream)
{
    const float* qt_emb = (const float*)d_in[0];
    const float* nd_emb = (const float*)d_in[1];
    const float* sa_w  = (const float*)d_in[2];
    const float* sa_b  = (const float*)d_in[3];
    const float* sa_ow = (const float*)d_in[4];
    const float* sa_ob = (const float*)d_in[5];
    const float* ca_w  = (const float*)d_in[6];
    const float* ca_b  = (const float*)d_in[7];
    const float* ca_ow = (const float*)d_in[8];
    const float* ca_ob = (const float*)d_in[9];
    const float* ln1w  = (const float*)d_in[10];
    const float* ln1b  = (const float*)d_in[11];
    const float* ln2w  = (const float*)d_in[12];
    const float* ln2b  = (const float*)d_in[13];
    const float* ln3w  = (const float*)d_in[14];
    const float* ln3b  = (const float*)d_in[15];
    const float* f1w   = (const float*)d_in[16];
    const float* f1b   = (const float*)d_in[17];
    const float* f2w   = (const float*)d_in[18];
    const float* f2b   = (const float*)d_in[19];
    const float* fnw   = (const float*)d_in[20];
    const float* fnb   = (const float*)d_in[21];

    char* base = (char*)d_ws;
    int*   idxb = (int*)base;                                      // 35,840 B
    float* x    = (float*)(base + 35840);                          // 13.76 MB
    unsigned short* hbuf  = (unsigned short*)(base + 13798400);    // 6.88 MB
    unsigned short* memb  = (unsigned short*)(base + 20679680);
    unsigned short* mem2  = (unsigned short*)(base + 27560960);
    unsigned short* obuf  = (unsigned short*)(base + 34442240);
    unsigned short* qbuf  = (unsigned short*)(base + 41323520);
    unsigned short* qkv   = (unsigned short*)(base + 48204800);    // 20.6 MB
    unsigned short* kvbuf = (unsigned short*)(base + 68848640);    // 13.76 MB
    unsigned short* ffn1  = (unsigned short*)(base + 82611200);    // 27.5 MB
    unsigned short* wsa   = (unsigned short*)(base + 110136320);
    unsigned short* wsao  = wsa  + 2654208;
    unsigned short* wca   = wsao + 884736;
    unsigned short* wcao  = wca  + 2654208;
    unsigned short* wf1   = wcao + 884736;
    unsigned short* wf2   = wf1  + 3538944;
    float* simb = (float*)(base + 48204800);   // overlaps qkv+kvbuf (dead later)

    // weight conversion (re-done every call; inputs restored each call)
    cvt_kernel<<<(663552 + 255) / 256, 256, 0, stream>>>((const float4*)sa_w,  (ushort4*)wsa,  663552);
    cvt_kernel<<<(221184 + 255) / 256, 256, 0, stream>>>((const float4*)sa_ow, (ushort4*)wsao, 221184);
    cvt_kernel<<<(663552 + 255) / 256, 256, 0, stream>>>((const float4*)ca_w,  (ushort4*)wca,  663552);
    cvt_kernel<<<(221184 + 255) / 256, 256, 0, stream>>>((const float4*)ca_ow, (ushort4*)wcao, 221184);
    cvt_kernel<<<(884736 + 255) / 256, 256, 0, stream>>>((const float4*)f1w,   (ushort4*)wf1,  884736);
    cvt_kernel<<<(884736 + 255) / 256, 256, 0, stream>>>((const float4*)f2w,   (ushort4*)wf2,  884736);

    // phase 1: retrieval
    sim_kernel<<<dim3(NN / 128, NB), 256, 0, stream>>>(qt_emb, nd_emb, simb);
    topk_kernel<<<NB * SEQ, 256, 0, stream>>>(simb, idxb);
    build_kernel<<<NSEQ, 256, 0, stream>>>(qt_emb, nd_emb, idxb, x, memb);

    // phase 2: transformer
    for (int i = 0; i < 6; ++i) {
        const unsigned short* memory = (i < 3) ? memb : mem2;
        // self-attention
        ln_kernel<1><<<MROWS, 128, 0, stream>>>(x, ln1w + i * D, ln1b + i * D, hbuf, nullptr);
        mm_kernel<128,1,0,0><<<dim3(1152/128, MROWS/128), 256, 0, stream>>>(
            hbuf, wsa + (size_t)i * 1152 * D, sa_b + i * 1152, nullptr, qkv, MROWS, 1152, D);
        attn_kernel<<<dim3(NSEQ, NH), 256, 0, stream>>>(qkv, 1152, qkv, 1152, 384, 768, obuf);
        mm_kernel<64,0,0,1><<<dim3(384/64, MROWS/128), 256, 0, stream>>>(
            obuf, wsao + (size_t)i * D * D, sa_ob + i * D, x, x, MROWS, D, D);
        // cross-attention
        ln_kernel<1><<<MROWS, 128, 0, stream>>>(x, ln2w + i * D, ln2b + i * D, hbuf, nullptr);
        mm_kernel<64,1,0,0><<<dim3(384/64, MROWS/128), 256, 0, stream>>>(
            hbuf, wca + (size_t)i * 1152 * D, ca_b + i * 1152, nullptr, qbuf, MROWS, D, D);
        mm_kernel<128,1,0,0><<<dim3(768/128, MROWS/128), 256, 0, stream>>>(
            memory, wca + (size_t)i * 1152 * D + 384 * D, ca_b + i * 1152 + 384,
            nullptr, kvbuf, MROWS, 768, D);
        attn_kernel<<<dim3(NSEQ, NH), 256, 0, stream>>>(qbuf, 384, kvbuf, 768, 0, 384, obuf);
        mm_kernel<64,0,0,1><<<dim3(384/64, MROWS/128), 256, 0, stream>>>(
            obuf, wcao + (size_t)i * D * D, ca_ob + i * D, x, x, MROWS, D, D);
        // ffn
        ln_kernel<1><<<MROWS, 128, 0, stream>>>(x, ln3w + i * D, ln3b + i * D, hbuf, nullptr);
        mm_kernel<128,1,1,0><<<dim3(1536/128, MROWS/128), 256, 0, stream>>>(
            hbuf, wf1 + (size_t)i * 1536 * D, f1b + i * 1536, nullptr, ffn1, MROWS, 1536, D);
        mm_kernel<64,0,0,1><<<dim3(384/64, MROWS/128), 256, 0, stream>>>(
            ffn1, wf2 + (size_t)i * D * 1536, f2b + i * D, x, x, MROWS, D, 1536);
        if (i == 2) {  // mid final-norm: x <- LN(x) (fp32, in-place), mem2 = bf16(x)
            ln_kernel<0><<<MROWS, 128, 0, stream>>>(x, fnw, fnb, x, mem2);
        }
    }
    ln_kernel<0><<<MROWS, 128, 0, stream>>>(x, fnw + D, fnb + D, d_out, nullptr);
}